// Round 15
// baseline (1949.528 us; speedup 1.0000x reference)
//
#include <hip/hip_runtime.h>
#include <math.h>

#define VOCAB  32000
#define EMB    256
#define HID    512
#define MAXLEN 512
#define BATCH  128
#define NCLASS 2

#define NBG 8     // batch groups (16 rows each)
#define NJG 2     // col groups (256 cols each)
#define RPB 16    // rows per block
#define CPB 256   // cols per block
#define KP  520   // padded k stride (bf16 elems) for hsb rows
#define SBP 68    // W stage buffer row stride (bf16 elems)

typedef __attribute__((ext_vector_type(8))) short bf16x8;
typedef __attribute__((ext_vector_type(4))) float f32x4;

// round-to-nearest-even fp32 -> bf16 (bit form)
__device__ __forceinline__ unsigned short f2b_bits(unsigned int u) {
    return (unsigned short)((u + 0x7fffu + ((u >> 16) & 1u)) >> 16);
}

// ---------------------------------------------------------------------------
// Kernel A: embW[v][j] = b_h[j] + sum_e emb[v][e] * W_ih[e][j]  (fp32, exact)
// (unchanged — ~70 us)
// ---------------------------------------------------------------------------
__global__ __launch_bounds__(256, 1) void embw_kernel(
    const float* __restrict__ emb, const float* __restrict__ W_ih,
    const float* __restrict__ b_h, float* __restrict__ embW)
{
    __shared__ __align__(16) float aT[EMB][64];
    __shared__ __align__(16) float wS[32][HID];

    const int t    = threadIdx.x;
    const int row0 = blockIdx.x * 64;

    {
        const int row   = t >> 2;
        const int elane = t & 3;
        for (int i = 0; i < 16; ++i) {
            const int e = elane * 4 + i * 16;
            const float4 v = *reinterpret_cast<const float4*>(
                &emb[(size_t)(row0 + row) * EMB + e]);
            aT[e + 0][row] = v.x;
            aT[e + 1][row] = v.y;
            aT[e + 2][row] = v.z;
            aT[e + 3][row] = v.w;
        }
    }

    const int rg = t >> 5;
    const int cg = t & 31;

    float acc[8][16];
    #pragma unroll
    for (int r = 0; r < 8; ++r)
        #pragma unroll
        for (int c = 0; c < 16; ++c) acc[r][c] = 0.f;

    for (int ec = 0; ec < 8; ++ec) {
        __syncthreads();
        {
            const int j4  = (t & 127) * 4;
            const int keb = (t >> 7);
            #pragma unroll
            for (int i = 0; i < 16; ++i) {
                const int ke = keb + i * 2;
                const float4 v = *reinterpret_cast<const float4*>(
                    &W_ih[(size_t)(ec * 32 + ke) * HID + j4]);
                *reinterpret_cast<float4*>(&wS[ke][j4]) = v;
            }
        }
        __syncthreads();

        for (int ke = 0; ke < 32; ++ke) {
            float a8[8];
            *(float4*)&a8[0] = *(const float4*)&aT[ec * 32 + ke][rg * 8];
            *(float4*)&a8[4] = *(const float4*)&aT[ec * 32 + ke][rg * 8 + 4];
            float w16[16];
            #pragma unroll
            for (int q = 0; q < 4; ++q)
                *(float4*)&w16[q * 4] =
                    *(const float4*)&wS[ke][cg * 16 + q * 4];
            #pragma unroll
            for (int r = 0; r < 8; ++r)
                #pragma unroll
                for (int c = 0; c < 16; ++c)
                    acc[r][c] = fmaf(a8[r], w16[c], acc[r][c]);
        }
    }

    float bh[16];
    #pragma unroll
    for (int q = 0; q < 4; ++q)
        *(float4*)&bh[q * 4] = *(const float4*)&b_h[cg * 16 + q * 4];
    #pragma unroll
    for (int r = 0; r < 8; ++r) {
        const size_t orow = (size_t)(row0 + rg * 8 + r) * HID + cg * 16;
        #pragma unroll
        for (int q = 0; q < 4; ++q) {
            float4 v;
            v.x = acc[r][q * 4 + 0] + bh[q * 4 + 0];
            v.y = acc[r][q * 4 + 1] + bh[q * 4 + 1];
            v.z = acc[r][q * 4 + 2] + bh[q * 4 + 2];
            v.w = acc[r][q * 4 + 3] + bh[q * 4 + 3];
            *reinterpret_cast<float4*>(&embW[orow + q * 4]) = v;
        }
    }
}

// ---------------------------------------------------------------------------
// Kernel B: sequential RNN — 32 W-fragments/thread in VGPRs, 256 cols/block,
// pairwise flag exchange (fan-in 1).
// R13 lessons applied: (a) B-frags in registers verified (conflict counter
//   halved) -> scale to 32 frags (128 VGPR, cap 256 @ 2 waves/SIMD);
//   (b) Wb LDS was dead after the frag pull -> dropped; W staged chunk-wise
//   through a 34KB reusable buffer (fully-unrolled chunk loop => all frag
//   indices compile-time static, rule #20).
// 16 blocks x 512 threads: block (bgrp=bid&7, jgrp=bid>>3) owns 16 rows x
//   256 cols. Partner = bid^8 (same XCD under round-robin — perf-only).
// Exchange: publish fp32 (relaxed agent) -> __syncthreads (vmcnt drain) ->
//   t0 RELEASE-stores flag=ts+1; partner t0 ACQUIRE-spins flag>=ts.
//   ONE agent round-trip/step (central counter needed two). Skew <=1 =>
//   2-buffer ping-pong safe (same invariant as R4-R13; proven protocol
//   primitives, only the graph shrank).
// MFMA: wave w owns col-tiles 2w,2w+1 (cols j0+32w..+31). A-frag (h rows)
//   shared by both tiles: 16 A ds_read_b128 feed 32 MFMAs/step.
// ---------------------------------------------------------------------------
__global__ __launch_bounds__(512, 2) void rnn_kernel(
    const int* __restrict__ inputs, const float* __restrict__ embW,
    const float* __restrict__ W_hh, float* hA, float* hB,
    int* flags)
{
    __shared__ __align__(16) unsigned short Sb[CPB][SBP];  // 34,816 B (W stage)
    __shared__ __align__(16) unsigned short hsb[RPB][KP];  // 16,640 B

    const int t    = threadIdx.x;
    const int w    = t >> 6;          // wave 0..7
    const int l    = t & 63;
    const int lm   = l & 15;          // MFMA row/col lane index
    const int lk   = l >> 4;          // MFMA k-group / D row group
    const int ko   = lk * 8;
    const int bid  = blockIdx.x;
    const int bgrp = bid & 7;
    const int jgrp = bid >> 3;        // 0 or 1
    const int j0   = jgrp * CPB;
    const int r0   = bgrp * RPB;

    // ---- one-time: W -> 32 B-frags in VGPRs, via 8 staged 64-k chunks ----
    bf16x8 Bf[2][16];
    {
        const int col = t & 255;
        const int k2  = t >> 8;       // 0 or 1
        #pragma unroll
        for (int c = 0; c < 8; ++c) {
            for (int i = 0; i < 32; ++i) {
                const int kk = i * 2 + k2;
                const int k  = c * 64 + kk;
                Sb[col][kk] = f2b_bits(__builtin_bit_cast(unsigned int,
                                  W_hh[(size_t)k * HID + j0 + col]));
            }
            __syncthreads();
            #pragma unroll
            for (int ct = 0; ct < 2; ++ct) {
                #pragma unroll
                for (int kh = 0; kh < 2; ++kh) {
                    Bf[ct][c * 2 + kh] = *(const bf16x8*)
                        &Sb[w * 32 + ct * 16 + lm][kh * 32 + ko];
                }
            }
            __syncthreads();
        }
    }

    for (int ts = 0; ts < MAXLEN; ++ts) {
        const float* hc = (ts & 1) ? hB : hA;
        float*       hn = (ts & 1) ? hA : hB;

        // ---- wait for partner's previous-step publish (t0 acquire) ----
        if (ts > 0) {
            if (t == 0) {
                const int pf = bgrp * NJG + (jgrp ^ 1);
                while (__hip_atomic_load(&flags[pf], __ATOMIC_ACQUIRE,
                                         __HIP_MEMORY_SCOPE_AGENT) < ts) {
                    __builtin_amdgcn_s_sleep(1);
                }
            }
            __syncthreads();
        }

        // ---- stage 16 h rows (full K=512): fp32 agent loads -> bf16 LDS ----
        #pragma unroll
        for (int q = 0; q < 2; ++q) {
            const int chunk = t + q * 512;        // 0..1023
            const int row   = chunk >> 6;         // 0..15
            const int kc    = (chunk & 63) * 8;   // 0..504
            const unsigned long long* src = (const unsigned long long*)
                &hc[(size_t)(r0 + row) * HID + kc];
            unsigned long long d0 = __hip_atomic_load(src + 0,
                __ATOMIC_RELAXED, __HIP_MEMORY_SCOPE_AGENT);
            unsigned long long d1 = __hip_atomic_load(src + 1,
                __ATOMIC_RELAXED, __HIP_MEMORY_SCOPE_AGENT);
            unsigned long long d2 = __hip_atomic_load(src + 2,
                __ATOMIC_RELAXED, __HIP_MEMORY_SCOPE_AGENT);
            unsigned long long d3 = __hip_atomic_load(src + 3,
                __ATOMIC_RELAXED, __HIP_MEMORY_SCOPE_AGENT);
            unsigned int q0 = (unsigned int)f2b_bits((unsigned int)d0) |
                              ((unsigned int)f2b_bits((unsigned int)(d0 >> 32)) << 16);
            unsigned int q1 = (unsigned int)f2b_bits((unsigned int)d1) |
                              ((unsigned int)f2b_bits((unsigned int)(d1 >> 32)) << 16);
            unsigned int q2 = (unsigned int)f2b_bits((unsigned int)d2) |
                              ((unsigned int)f2b_bits((unsigned int)(d2 >> 32)) << 16);
            unsigned int q3 = (unsigned int)f2b_bits((unsigned int)d3) |
                              ((unsigned int)f2b_bits((unsigned int)(d3 >> 32)) << 16);
            *(unsigned long long*)&hsb[row][kc] =
                (unsigned long long)q0 | ((unsigned long long)q1 << 32);
            *(unsigned long long*)&hsb[row][kc + 4] =
                (unsigned long long)q2 | ((unsigned long long)q3 << 32);
        }

        // ---- feedforward gather: 4 rows x 2 col-tiles (fp32) ----
        float ev[2][4];
        #pragma unroll
        for (int i = 0; i < 4; ++i) {
            const int r   = lk * 4 + i;
            const int tok = inputs[(r0 + r) * MAXLEN + ts];
            ev[0][i] = embW[(size_t)tok * HID + j0 + w * 32 + lm];
            ev[1][i] = embW[(size_t)tok * HID + j0 + w * 32 + 16 + lm];
        }
        __syncthreads();

        // ---- MFMA: 16 k-tiles x 2 col-tiles; A shared, B from VGPRs ----
        f32x4 a0e = {0.f, 0.f, 0.f, 0.f}, a0o = {0.f, 0.f, 0.f, 0.f};
        f32x4 a1e = {0.f, 0.f, 0.f, 0.f}, a1o = {0.f, 0.f, 0.f, 0.f};
        #pragma unroll
        for (int kt = 0; kt < 16; kt += 2) {
            const bf16x8 a0 = *(const bf16x8*)&hsb[lm][kt * 32 + ko];
            const bf16x8 a1 = *(const bf16x8*)&hsb[lm][(kt + 1) * 32 + ko];
            a0e = __builtin_amdgcn_mfma_f32_16x16x32_bf16(a0, Bf[0][kt],     a0e, 0, 0, 0);
            a1e = __builtin_amdgcn_mfma_f32_16x16x32_bf16(a0, Bf[1][kt],     a1e, 0, 0, 0);
            a0o = __builtin_amdgcn_mfma_f32_16x16x32_bf16(a1, Bf[0][kt + 1], a0o, 0, 0, 0);
            a1o = __builtin_amdgcn_mfma_f32_16x16x32_bf16(a1, Bf[1][kt + 1], a1o, 0, 0, 0);
        }
        const f32x4 c0 = a0e + a0o;
        const f32x4 c1 = a1e + a1o;

        // ---- tanh + publish (D lane: row = lk*4+i, col-tile base w*32) ----
        #pragma unroll
        for (int i = 0; i < 4; ++i) {
            const size_t rowoff = (size_t)(r0 + lk * 4 + i) * HID;
            const float s0 = tanhf(c0[i] + ev[0][i]);
            __hip_atomic_store(&hn[rowoff + j0 + w * 32 + lm], s0,
                               __ATOMIC_RELAXED, __HIP_MEMORY_SCOPE_AGENT);
            const float s1 = tanhf(c1[i] + ev[1][i]);
            __hip_atomic_store(&hn[rowoff + j0 + w * 32 + 16 + lm], s1,
                               __ATOMIC_RELAXED, __HIP_MEMORY_SCOPE_AGENT);
        }
        __syncthreads();   // vmcnt drain: all publish stores complete

        // ---- release our flag (monotone, one agent round-trip/step) ----
        if (t == 0)
            __hip_atomic_store(&flags[bgrp * NJG + jgrp], ts + 1,
                               __ATOMIC_RELEASE, __HIP_MEMORY_SCOPE_AGENT);
    }
    // final h in hA (MAXLEN even)
}

// ---------------------------------------------------------------------------
// Kernel C: logits = hA @ W_out + b_out, sigmoid. Tiny. (fp32, unchanged)
// ---------------------------------------------------------------------------
__global__ void head_kernel(const float* __restrict__ h_final,
                            const float* __restrict__ W_out,
                            const float* __restrict__ b_out,
                            float* __restrict__ out)
{
    const int t = threadIdx.x;
    const int b = t >> 1, c = t & 1;
    float acc = b_out[c];
    for (int k = 0; k < HID; ++k)
        acc = fmaf(h_final[(size_t)b * HID + k], W_out[k * NCLASS + c], acc);
    out[t] = 1.f / (1.f + expf(-acc));
}

// ---------------------------------------------------------------------------
extern "C" void kernel_launch(void* const* d_in, const int* in_sizes, int n_in,
                              void* d_out, int out_size, void* d_ws,
                              size_t ws_size, hipStream_t stream)
{
    const int*   inputs = (const int*)  d_in[0];
    const float* emb    = (const float*)d_in[1];
    const float* W_ih   = (const float*)d_in[2];
    const float* W_hh   = (const float*)d_in[3];
    const float* b_h    = (const float*)d_in[4];
    const float* W_out  = (const float*)d_in[5];
    const float* b_out  = (const float*)d_in[6];
    float* out = (float*)d_out;

    // ws layout: embW 64 MB | hA 256 KB | hB 256 KB | flags 64 B
    float* embW  = (float*)d_ws;
    float* hA    = embW + (size_t)VOCAB * HID;
    float* hB    = hA + (size_t)BATCH * HID;
    int*   flags = (int*)(hB + (size_t)BATCH * HID);

    // per-launch re-init (graph-capture-safe, deterministic)
    hipMemsetAsync(hA, 0, (size_t)BATCH * HID * sizeof(float), stream);
    hipMemsetAsync(flags, 0, (size_t)NBG * NJG * sizeof(int), stream);

    embw_kernel<<<VOCAB / 64, 256, 0, stream>>>(emb, W_ih, b_h, embW);
    rnn_kernel<<<NBG * NJG, 512, 0, stream>>>(inputs, embW, W_hh,
                                              hA, hB, flags);
    head_kernel<<<1, 256, 0, stream>>>(hA, W_out, b_out, out);
}

// Round 16
// 1426.223 us; speedup vs baseline: 1.3669x; 1.3669x over previous
//
#include <hip/hip_runtime.h>
#include <math.h>

#define VOCAB  32000
#define EMB    256
#define HID    512
#define MAXLEN 512
#define BATCH  128
#define NCLASS 2

#define NBG 8     // batch groups (16 rows each)
#define NJG 4     // col groups (128 cols each)
#define RPB 16    // rows per block
#define CPB 128   // cols per block
#define KP  520   // padded k stride (bf16 elems) for Wb/hsb rows

typedef __attribute__((ext_vector_type(8))) short bf16x8;
typedef __attribute__((ext_vector_type(4))) float f32x4;

// round-to-nearest-even fp32 -> bf16 (bit form)
__device__ __forceinline__ unsigned short f2b_bits(unsigned int u) {
    return (unsigned short)((u + 0x7fffu + ((u >> 16) & 1u)) >> 16);
}

// ---------------------------------------------------------------------------
// Kernel A: embW[v][j] = b_h[j] + sum_e emb[v][e] * W_ih[e][j]  (fp32, exact)
// (unchanged — ~70 us)
// ---------------------------------------------------------------------------
__global__ __launch_bounds__(256, 1) void embw_kernel(
    const float* __restrict__ emb, const float* __restrict__ W_ih,
    const float* __restrict__ b_h, float* __restrict__ embW)
{
    __shared__ __align__(16) float aT[EMB][64];
    __shared__ __align__(16) float wS[32][HID];

    const int t    = threadIdx.x;
    const int row0 = blockIdx.x * 64;

    {
        const int row   = t >> 2;
        const int elane = t & 3;
        for (int i = 0; i < 16; ++i) {
            const int e = elane * 4 + i * 16;
            const float4 v = *reinterpret_cast<const float4*>(
                &emb[(size_t)(row0 + row) * EMB + e]);
            aT[e + 0][row] = v.x;
            aT[e + 1][row] = v.y;
            aT[e + 2][row] = v.z;
            aT[e + 3][row] = v.w;
        }
    }

    const int rg = t >> 5;
    const int cg = t & 31;

    float acc[8][16];
    #pragma unroll
    for (int r = 0; r < 8; ++r)
        #pragma unroll
        for (int c = 0; c < 16; ++c) acc[r][c] = 0.f;

    for (int ec = 0; ec < 8; ++ec) {
        __syncthreads();
        {
            const int j4  = (t & 127) * 4;
            const int keb = (t >> 7);
            #pragma unroll
            for (int i = 0; i < 16; ++i) {
                const int ke = keb + i * 2;
                const float4 v = *reinterpret_cast<const float4*>(
                    &W_ih[(size_t)(ec * 32 + ke) * HID + j4]);
                *reinterpret_cast<float4*>(&wS[ke][j4]) = v;
            }
        }
        __syncthreads();

        for (int ke = 0; ke < 32; ++ke) {
            float a8[8];
            *(float4*)&a8[0] = *(const float4*)&aT[ec * 32 + ke][rg * 8];
            *(float4*)&a8[4] = *(const float4*)&aT[ec * 32 + ke][rg * 8 + 4];
            float w16[16];
            #pragma unroll
            for (int q = 0; q < 4; ++q)
                *(float4*)&w16[q * 4] =
                    *(const float4*)&wS[ke][cg * 16 + q * 4];
            #pragma unroll
            for (int r = 0; r < 8; ++r)
                #pragma unroll
                for (int c = 0; c < 16; ++c)
                    acc[r][c] = fmaf(a8[r], w16[c], acc[r][c]);
        }
    }

    float bh[16];
    #pragma unroll
    for (int q = 0; q < 4; ++q)
        *(float4*)&bh[q * 4] = *(const float4*)&b_h[cg * 16 + q * 4];
    #pragma unroll
    for (int r = 0; r < 8; ++r) {
        const size_t orow = (size_t)(row0 + rg * 8 + r) * HID + cg * 16;
        #pragma unroll
        for (int q = 0; q < 4; ++q) {
            float4 v;
            v.x = acc[r][q * 4 + 0] + bh[q * 4 + 0];
            v.y = acc[r][q * 4 + 1] + bh[q * 4 + 1];
            v.z = acc[r][q * 4 + 2] + bh[q * 4 + 2];
            v.w = acc[r][q * 4 + 3] + bh[q * 4 + 3];
            *reinterpret_cast<float4*>(&embW[orow + q * 4]) = v;
        }
    }
}

// ---------------------------------------------------------------------------
// Kernel B: sequential RNN — R13 structure (bf16 MFMA, 16 B-frags in VGPRs,
// central-counter barrier) with the h EXCHANGE IN BF16.
// R14 lesson: fan-in-1 doubled per-block epilogue and halved CUs for zero
//   exchange gain (visibility-bound, not round-trip-bound) — reverted.
// bf16 exchange is BIT-IDENTICAL for the recurrence: R13 staged f2b(load);
//   now we publish f2b(tanh) and stage a straight copy. Staging per thread:
//   8 ull atomic loads + ~24 pack ops -> 4 ull loads + 4 ull writes (both
//   sides canonical sequential 1KB/wave, conflict-free). Publish: 2B
//   stores, drain halves. Head precision preserved: at ts==MAXLEN-1 each
//   thread also stores fp32 tanh to h_final (read by head_kernel).
// 32 blocks x 512 threads: block (bgrp=bid&7, jgrp=bid>>3) owns 16 rows x
//   128 cols. MFMA 16x16x32 layouts per guide §3 (R11-R14 ref-passed).
// ---------------------------------------------------------------------------
__global__ __launch_bounds__(512, 1) void rnn_kernel(
    const int* __restrict__ inputs, const float* __restrict__ embW,
    const float* __restrict__ W_hh, unsigned short* hA, unsigned short* hB,
    float* h_final, int* bar)
{
    __shared__ __align__(16) unsigned short Wb[CPB][KP];   // 133,120 B
    __shared__ __align__(16) unsigned short hsb[RPB][KP];  // 16,640 B

    const int t    = threadIdx.x;
    const int w    = t >> 6;          // wave 0..7 = col-tile
    const int l    = t & 63;
    const int lm   = l & 15;          // MFMA row/col lane index
    const int lk   = l >> 4;          // MFMA k-group / D row group
    const int ko   = lk * 8;
    const int bid  = blockIdx.x;
    const int bgrp = bid & 7;
    const int jgrp = bid >> 3;
    const int j0   = jgrp * CPB;
    const int r0   = bgrp * RPB;

    // ---- one-time: stage W slice to bf16 LDS [col][k] ----
    {
        const int c  = t & 127;       // local col
        const int kq = t >> 7;        // k quarter
        for (int i = 0; i < 128; i += 4) {
            const int k = kq * 128 + i;
            unsigned int u0 = __builtin_bit_cast(unsigned int,
                                W_hh[(size_t)(k + 0) * HID + j0 + c]);
            unsigned int u1 = __builtin_bit_cast(unsigned int,
                                W_hh[(size_t)(k + 1) * HID + j0 + c]);
            unsigned int u2 = __builtin_bit_cast(unsigned int,
                                W_hh[(size_t)(k + 2) * HID + j0 + c]);
            unsigned int u3 = __builtin_bit_cast(unsigned int,
                                W_hh[(size_t)(k + 3) * HID + j0 + c]);
            unsigned int p0 = (unsigned int)f2b_bits(u0) |
                              ((unsigned int)f2b_bits(u1) << 16);
            unsigned int p1 = (unsigned int)f2b_bits(u2) |
                              ((unsigned int)f2b_bits(u3) << 16);
            *(unsigned long long*)&Wb[c][k] =
                (unsigned long long)p0 | ((unsigned long long)p1 << 32);
        }
    }
    __syncthreads();

    // ---- one-time: pull this thread's 16 B-fragments into registers ----
    const unsigned short* wrow = &Wb[w * 16 + lm][0];
    const bf16x8 B00 = *(const bf16x8*)&wrow[ 0 * 32 + ko];
    const bf16x8 B01 = *(const bf16x8*)&wrow[ 1 * 32 + ko];
    const bf16x8 B02 = *(const bf16x8*)&wrow[ 2 * 32 + ko];
    const bf16x8 B03 = *(const bf16x8*)&wrow[ 3 * 32 + ko];
    const bf16x8 B04 = *(const bf16x8*)&wrow[ 4 * 32 + ko];
    const bf16x8 B05 = *(const bf16x8*)&wrow[ 5 * 32 + ko];
    const bf16x8 B06 = *(const bf16x8*)&wrow[ 6 * 32 + ko];
    const bf16x8 B07 = *(const bf16x8*)&wrow[ 7 * 32 + ko];
    const bf16x8 B08 = *(const bf16x8*)&wrow[ 8 * 32 + ko];
    const bf16x8 B09 = *(const bf16x8*)&wrow[ 9 * 32 + ko];
    const bf16x8 B10 = *(const bf16x8*)&wrow[10 * 32 + ko];
    const bf16x8 B11 = *(const bf16x8*)&wrow[11 * 32 + ko];
    const bf16x8 B12 = *(const bf16x8*)&wrow[12 * 32 + ko];
    const bf16x8 B13 = *(const bf16x8*)&wrow[13 * 32 + ko];
    const bf16x8 B14 = *(const bf16x8*)&wrow[14 * 32 + ko];
    const bf16x8 B15 = *(const bf16x8*)&wrow[15 * 32 + ko];

    for (int ts = 0; ts < MAXLEN; ++ts) {
        const unsigned short* hc = (ts & 1) ? hB : hA;
        unsigned short*       hn = (ts & 1) ? hA : hB;

        // ---- stage 16 h rows (bf16 straight copy, 1KB/wave sequential) ----
        #pragma unroll
        for (int q = 0; q < 2; ++q) {
            const int row = (t >> 6) + q * 8;     // 0..15
            const int kc  = (t & 63) * 8;         // bf16 col, step 8
            const unsigned long long* src = (const unsigned long long*)
                &hc[(size_t)(r0 + row) * HID + kc];
            unsigned long long d0 = __hip_atomic_load(src + 0,
                __ATOMIC_RELAXED, __HIP_MEMORY_SCOPE_AGENT);
            unsigned long long d1 = __hip_atomic_load(src + 1,
                __ATOMIC_RELAXED, __HIP_MEMORY_SCOPE_AGENT);
            *(unsigned long long*)&hsb[row][kc]     = d0;
            *(unsigned long long*)&hsb[row][kc + 4] = d1;
        }

        // ---- feedforward gather for this lane's 4 output rows (fp32) ----
        float ev[4];
        #pragma unroll
        for (int i = 0; i < 4; ++i) {
            const int r   = lk * 4 + i;
            const int tok = inputs[(r0 + r) * MAXLEN + ts];
            ev[i] = embW[(size_t)tok * HID + j0 + w * 16 + lm];
        }
        __syncthreads();

        // ---- MFMA: 16 k-tiles, A from hsb, B from registers ----
        f32x4 ae = {0.f, 0.f, 0.f, 0.f};
        f32x4 ao = {0.f, 0.f, 0.f, 0.f};
#define MF2(k0, Ba, Bb)                                                       \
        {                                                                     \
            const bf16x8 a0 = *(const bf16x8*)&hsb[lm][(k0) * 32 + ko];       \
            ae = __builtin_amdgcn_mfma_f32_16x16x32_bf16(a0, Ba, ae, 0, 0, 0);\
            const bf16x8 a1 = *(const bf16x8*)&hsb[lm][(k0 + 1) * 32 + ko];   \
            ao = __builtin_amdgcn_mfma_f32_16x16x32_bf16(a1, Bb, ao, 0, 0, 0);\
        }
        MF2( 0, B00, B01); MF2( 2, B02, B03);
        MF2( 4, B04, B05); MF2( 6, B06, B07);
        MF2( 8, B08, B09); MF2(10, B10, B11);
        MF2(12, B12, B13); MF2(14, B14, B15);
#undef MF2
        const f32x4 cc = ae + ao;

        // ---- tanh + publish bf16 (+ fp32 h_final on the last step) ----
        #pragma unroll
        for (int i = 0; i < 4; ++i) {
            const float s = tanhf(cc[i] + ev[i]);
            const unsigned short sb =
                f2b_bits(__builtin_bit_cast(unsigned int, s));
            const size_t off =
                (size_t)(r0 + lk * 4 + i) * HID + j0 + w * 16 + lm;
            __hip_atomic_store(&hn[off], sb,
                               __ATOMIC_RELAXED, __HIP_MEMORY_SCOPE_AGENT);
            if (ts == MAXLEN - 1) h_final[off] = s;
        }
        __syncthreads();   // vmcnt drain: publish stores complete

        // ---- central 4-block barrier (R4/R11/R13-proven protocol) ----
        if (t == 0) {
            int* c = &bar[bgrp * MAXLEN + ts];
            __hip_atomic_fetch_add(c, 1, __ATOMIC_ACQ_REL,
                                   __HIP_MEMORY_SCOPE_AGENT);
            while (__hip_atomic_load(c, __ATOMIC_ACQUIRE,
                                     __HIP_MEMORY_SCOPE_AGENT) < NJG) {
                __builtin_amdgcn_s_sleep(1);
            }
        }
        __syncthreads();
    }
}

// ---------------------------------------------------------------------------
// Kernel C: logits = h_final @ W_out + b_out, sigmoid. Tiny. (fp32 input)
// ---------------------------------------------------------------------------
__global__ void head_kernel(const float* __restrict__ h_final,
                            const float* __restrict__ W_out,
                            const float* __restrict__ b_out,
                            float* __restrict__ out)
{
    const int t = threadIdx.x;
    const int b = t >> 1, c = t & 1;
    float acc = b_out[c];
    for (int k = 0; k < HID; ++k)
        acc = fmaf(h_final[(size_t)b * HID + k], W_out[k * NCLASS + c], acc);
    out[t] = 1.f / (1.f + expf(-acc));
}

// ---------------------------------------------------------------------------
extern "C" void kernel_launch(void* const* d_in, const int* in_sizes, int n_in,
                              void* d_out, int out_size, void* d_ws,
                              size_t ws_size, hipStream_t stream)
{
    const int*   inputs = (const int*)  d_in[0];
    const float* emb    = (const float*)d_in[1];
    const float* W_ih   = (const float*)d_in[2];
    const float* W_hh   = (const float*)d_in[3];
    const float* b_h    = (const float*)d_in[4];
    const float* W_out  = (const float*)d_in[5];
    const float* b_out  = (const float*)d_in[6];
    float* out = (float*)d_out;

    // ws layout: embW 64MB | hA 128KB (bf16) | hB 128KB | h_final 256KB | bar
    float*          embW    = (float*)d_ws;
    unsigned short* hA      = (unsigned short*)(embW + (size_t)VOCAB * HID);
    unsigned short* hB      = hA + (size_t)BATCH * HID;
    float*          h_final = (float*)(hB + (size_t)BATCH * HID);
    int*            bar     = (int*)(h_final + (size_t)BATCH * HID);

    // per-launch re-init (graph-capture-safe, deterministic)
    hipMemsetAsync(hA, 0, (size_t)BATCH * HID * sizeof(unsigned short), stream);
    hipMemsetAsync(bar, 0, (size_t)NBG * MAXLEN * sizeof(int), stream);

    embw_kernel<<<VOCAB / 64, 256, 0, stream>>>(emb, W_ih, b_h, embW);
    rnn_kernel<<<NBG * NJG, 512, 0, stream>>>(inputs, embW, W_hh,
                                              hA, hB, h_final, bar);
    head_kernel<<<1, 256, 0, stream>>>(h_final, W_out, b_out, out);
}